// Round 1
// baseline (643.639 us; speedup 1.0000x reference)
//
#include <hip/hip_runtime.h>
#include <hip/hip_bf16.h>
#include <stdint.h>

// ---------------------------------------------------------------------------
// NNEmb: x = mean(W[ids], seq) ; sims = cos(x, train) ; argmax/max over train
// Outputs (float32, concatenated): y_pred[1024], scores[1024]
// ---------------------------------------------------------------------------

#define EPS 1e-8f

typedef __attribute__((ext_vector_type(8))) short bf16x8;
typedef __attribute__((ext_vector_type(4))) float f32x4;

__device__ __forceinline__ unsigned short f2bf(float f) {
    unsigned int b = __float_as_uint(f);
    unsigned int r = (b + 0x7fffu + ((b >> 16) & 1u)) >> 16;   // round-nearest-even
    return (unsigned short)r;
}
__device__ __forceinline__ float bf2f(unsigned short u) {
    return __uint_as_float(((unsigned int)u) << 16);
}

constexpr int SEQ = 200;
constexpr int B_  = 1024;    // batch
constexpr int D_  = 300;     // embedding dim (K)
constexpr int DP  = 320;     // K padded to multiple of 32
constexpr int NT  = 100000;  // train rows

// ---------------------------------------------------------------------------
// K1: mean-pool (fp64 accumulate), write x fp32, x_hi/x_lo bf16 (zero-padded
// K 300..319), and 1/max(||x||,eps).
// ---------------------------------------------------------------------------
__global__ __launch_bounds__(320) void pool_kernel(
    const int* __restrict__ ids, const float* __restrict__ W,
    float* __restrict__ x, unsigned short* __restrict__ xh,
    unsigned short* __restrict__ xl, float* __restrict__ rxn)
{
    const int b = blockIdx.x;
    const int d = threadIdx.x;
    double acc = 0.0;
    if (d < D_) {
        for (int s = 0; s < SEQ; ++s) {
            int id = ids[s * B_ + b];            // uniform per block -> scalar load
            acc += (double)W[(size_t)id * D_ + d];
        }
    }
    float xv = (float)(acc * (1.0 / SEQ));
    __shared__ float red[320];
    red[d] = (d < D_) ? xv * xv : 0.0f;
    __syncthreads();
    if (d < 64) {
        float s = 0.f;
        for (int i = d; i < 320; i += 64) s += red[i];
        #pragma unroll
        for (int m = 32; m >= 1; m >>= 1) s += __shfl_xor(s, m, 64);
        if (d == 0) rxn[b] = 1.0f / fmaxf(sqrtf(s), EPS);
    }
    if (d < D_) {
        x[(size_t)b * D_ + d] = xv;
        unsigned short h = f2bf(xv);
        xh[(size_t)b * DP + d] = h;
        xl[(size_t)b * DP + d] = f2bf(xv - bf2f(h));
    } else {
        xh[(size_t)b * DP + d] = 0;
        xl[(size_t)b * DP + d] = 0;
    }
}

// ---------------------------------------------------------------------------
// K2: 1/max(||t||,eps) per train row. One wave per row.
// ---------------------------------------------------------------------------
__global__ __launch_bounds__(256) void tnorm_kernel(
    const float* __restrict__ T, float* __restrict__ rtn)
{
    const int n = blockIdx.x * 4 + (threadIdx.x >> 6);
    const int lane = threadIdx.x & 63;
    if (n >= NT) return;
    float s = 0.f;
    for (int d = lane; d < D_; d += 64) {
        float v = T[(size_t)n * D_ + d];
        s += v * v;
    }
    #pragma unroll
    for (int m = 32; m >= 1; m >>= 1) s += __shfl_xor(s, m, 64);
    if (lane == 0) rtn[n] = 1.0f / fmaxf(sqrtf(s), EPS);
}

// ---------------------------------------------------------------------------
// K4: split-bf16 GEMM (3 MFMA products: hh + hl + lh) + fused top-1.
// Block = 128x128 tile, 256 threads = 4 waves (2x2 of 64x64), BK=32, LDK=40
// (+8 bf16 pad -> uniform 8-way bank spread on ds_read_b128).
// Epilogue: sims -> packed (key<<32 | ~idx) -> quad shuffle-reduce ->
// atomicMax per batch row.
// ---------------------------------------------------------------------------
constexpr int BM = 128, BN = 128, BK = 32, LDK = 40;

__global__ __launch_bounds__(256, 2) void gemm_top_kernel(
    const unsigned short* __restrict__ Ah, const unsigned short* __restrict__ Al,
    const float* __restrict__ T, const float* __restrict__ rxn,
    const float* __restrict__ rtn, unsigned long long* __restrict__ packed)
{
    __shared__ unsigned short sAh[BM * LDK];
    __shared__ unsigned short sAl[BM * LDK];
    __shared__ unsigned short sBh[BN * LDK];
    __shared__ unsigned short sBl[BN * LDK];

    const int tid  = threadIdx.x;
    const int bM   = blockIdx.x;   // 8 M-tiles (fastest-varying -> L2 B reuse)
    const int bN   = blockIdx.y;   // 782 N-tiles
    const int lane = tid & 63;
    const int wid  = tid >> 6;
    const int wm   = wid >> 1, wn = wid & 1;
    const int quad = lane >> 4, l15 = lane & 15;

    f32x4 acc[4][4] = {};

    const int ar = tid >> 2, ak = (tid & 3) * 8;   // A staging: 4 thr/row of 32 bf16
    const int br = tid >> 3, bc = (tid & 7) * 4;   // B staging: 8 thr/row of 32 fp32

    for (int kp = 0; kp < DP; kp += BK) {
        // ---- stage A (pre-split bf16, zero-padded in global) ----
        #pragma unroll
        for (int i = 0; i < 2; ++i) {
            int r = i * 64 + ar;
            size_t go = (size_t)(bM * BM + r) * DP + kp + ak;
            *(uint4*)&sAh[r * LDK + ak] = *(const uint4*)&Ah[go];
            *(uint4*)&sAl[r * LDK + ak] = *(const uint4*)&Al[go];
        }
        // ---- stage B: fp32 -> bf16 hi/lo on the fly ----
        #pragma unroll
        for (int i = 0; i < 4; ++i) {
            int r = i * 32 + br;
            int n = bN * BN + r;
            int k = kp + bc;
            float4 v = make_float4(0.f, 0.f, 0.f, 0.f);
            if (n < NT && k < D_) v = *(const float4*)&T[(size_t)n * D_ + k];
            unsigned short h0 = f2bf(v.x), h1 = f2bf(v.y), h2 = f2bf(v.z), h3 = f2bf(v.w);
            unsigned short l0 = f2bf(v.x - bf2f(h0)), l1 = f2bf(v.y - bf2f(h1));
            unsigned short l2 = f2bf(v.z - bf2f(h2)), l3 = f2bf(v.w - bf2f(h3));
            uint2 uh, ul;
            uh.x = (unsigned)h0 | ((unsigned)h1 << 16);
            uh.y = (unsigned)h2 | ((unsigned)h3 << 16);
            ul.x = (unsigned)l0 | ((unsigned)l1 << 16);
            ul.y = (unsigned)l2 | ((unsigned)l3 << 16);
            *(uint2*)&sBh[r * LDK + bc] = uh;
            *(uint2*)&sBl[r * LDK + bc] = ul;
        }
        __syncthreads();

        bf16x8 fah[4], fal[4], fbh[4], fbl[4];
        #pragma unroll
        for (int f = 0; f < 4; ++f) {
            int ro = (wm * 64 + f * 16 + l15) * LDK + quad * 8;
            fah[f] = *(const bf16x8*)&sAh[ro];
            fal[f] = *(const bf16x8*)&sAl[ro];
            int co = (wn * 64 + f * 16 + l15) * LDK + quad * 8;
            fbh[f] = *(const bf16x8*)&sBh[co];
            fbl[f] = *(const bf16x8*)&sBl[co];
        }
        #pragma unroll
        for (int fm = 0; fm < 4; ++fm) {
            #pragma unroll
            for (int fn = 0; fn < 4; ++fn) {
                acc[fm][fn] = __builtin_amdgcn_mfma_f32_16x16x32_bf16(fah[fm], fbh[fn], acc[fm][fn], 0, 0, 0);
                acc[fm][fn] = __builtin_amdgcn_mfma_f32_16x16x32_bf16(fah[fm], fbl[fn], acc[fm][fn], 0, 0, 0);
                acc[fm][fn] = __builtin_amdgcn_mfma_f32_16x16x32_bf16(fal[fm], fbh[fn], acc[fm][fn], 0, 0, 0);
            }
        }
        __syncthreads();
    }

    // ---- epilogue: sims + per-block top-1 per batch row ----
    float rt[4];
    const int gn0 = bN * BN + wn * 64 + l15;
    #pragma unroll
    for (int fn = 0; fn < 4; ++fn) {
        int gn = gn0 + fn * 16;
        rt[fn] = (gn < NT) ? rtn[gn] : 0.f;
    }
    #pragma unroll
    for (int fm = 0; fm < 4; ++fm) {
        #pragma unroll
        for (int r = 0; r < 4; ++r) {
            int gm = bM * BM + wm * 64 + fm * 16 + quad * 4 + r;  // C row = quad*4+reg
            float rx = rxn[gm];
            unsigned long long best = 0ull;
            #pragma unroll
            for (int fn = 0; fn < 4; ++fn) {
                int gn = gn0 + fn * 16;                            // C col = lane&15
                if (gn < NT) {
                    float sim = acc[fm][fn][r] * rx * rt[fn];
                    unsigned int b32 = __float_as_uint(sim);
                    unsigned int key = (b32 & 0x80000000u) ? ~b32 : (b32 | 0x80000000u);
                    unsigned long long pk =
                        ((unsigned long long)key << 32) | (unsigned int)(~gn);
                    best = (pk > best) ? pk : best;
                }
            }
            #pragma unroll
            for (int m = 1; m < 16; m <<= 1) {
                unsigned long long o = __shfl_xor(best, m, 64);
                best = (o > best) ? o : best;
            }
            if (l15 == 0 && best) atomicMax(&packed[gm], best);
        }
    }
}

// ---------------------------------------------------------------------------
// K5: decode winner, exact fp64 rescore for the score output, label gather.
// One wave per batch.
// ---------------------------------------------------------------------------
__global__ __launch_bounds__(64) void final_kernel(
    const unsigned long long* __restrict__ packed, const float* __restrict__ x,
    const float* __restrict__ T, const int* __restrict__ y_train,
    float* __restrict__ out)
{
    const int b = blockIdx.x;
    const int lane = threadIdx.x;
    unsigned long long key = packed[b];
    int idx = (int)(~(unsigned int)key);
    if (idx < 0 || idx >= NT) idx = 0;   // paranoia
    double dot = 0.0, nx = 0.0, nt = 0.0;
    for (int d = lane; d < D_; d += 64) {
        double xv = (double)x[(size_t)b * D_ + d];
        double tv = (double)T[(size_t)idx * D_ + d];
        dot += xv * tv; nx += xv * xv; nt += tv * tv;
    }
    #pragma unroll
    for (int m = 32; m >= 1; m >>= 1) {
        dot += __shfl_xor(dot, m, 64);
        nx  += __shfl_xor(nx, m, 64);
        nt  += __shfl_xor(nt, m, 64);
    }
    if (lane == 0) {
        double score = dot / (fmax(sqrt(nx), (double)EPS) * fmax(sqrt(nt), (double)EPS));
        out[b]        = (float)y_train[idx];
        out[B_ + b]   = (float)score;
    }
}

// ---------------------------------------------------------------------------
extern "C" void kernel_launch(void* const* d_in, const int* in_sizes, int n_in,
                              void* d_out, int out_size, void* d_ws, size_t ws_size,
                              hipStream_t stream)
{
    const int*   ids = (const int*)d_in[0];     // [200,1024]
    const float* W   = (const float*)d_in[1];   // [50000,300]
    const float* T   = (const float*)d_in[2];   // [100000,300]
    const int*   y   = (const int*)d_in[3];     // [100000]

    char* ws = (char*)d_ws;
    size_t off = 0;
    float* x            = (float*)(ws + off);           off += (size_t)B_ * D_ * 4;   // 1,228,800
    unsigned short* xh  = (unsigned short*)(ws + off);  off += (size_t)B_ * DP * 2;   //   655,360
    unsigned short* xl  = (unsigned short*)(ws + off);  off += (size_t)B_ * DP * 2;   //   655,360
    float* rxn          = (float*)(ws + off);           off += (size_t)B_ * 4;        //     4,096
    float* rtn          = (float*)(ws + off);           off += (size_t)NT * 4;        //   400,000
    unsigned long long* packed = (unsigned long long*)(ws + off);                     //     8,192

    hipMemsetAsync(packed, 0, (size_t)B_ * 8, stream);
    pool_kernel<<<B_, 320, 0, stream>>>(ids, W, x, xh, xl, rxn);
    tnorm_kernel<<<(NT + 3) / 4, 256, 0, stream>>>(T, rtn);
    gemm_top_kernel<<<dim3(B_ / BM, (NT + BN - 1) / BN), 256, 0, stream>>>(
        xh, xl, T, rxn, rtn, packed);
    final_kernel<<<B_, 64, 0, stream>>>(packed, x, T, y, (float*)d_out);
}

// Round 2
// 527.689 us; speedup vs baseline: 1.2197x; 1.2197x over previous
//
#include <hip/hip_runtime.h>
#include <hip/hip_bf16.h>
#include <stdint.h>

#define EPS 1e-8f

typedef __attribute__((ext_vector_type(8))) short bf16x8;
typedef __attribute__((ext_vector_type(4))) float f32x4;
typedef unsigned long long u64;
typedef unsigned int u32;

constexpr int SEQ = 200;
constexpr int B_  = 1024;    // batch
constexpr int D_  = 300;     // embedding dim
constexpr int DP  = 320;     // K padded
constexpr int NT  = 100000;  // train rows
constexpr int BM = 128, BN = 128, BK = 64;
constexpr int NBLK = (NT + BN - 1) / BN;   // 782
constexpr int CAND_MAX = 4096;
#define MARGIN 2e-3f

__device__ __forceinline__ unsigned short f2bf(float f) {   // RNE
    u32 b = __float_as_uint(f);
    return (unsigned short)((b + 0x7fffu + ((b >> 16) & 1u)) >> 16);
}
__device__ __forceinline__ u32 simkey(float s) {            // order-preserving
    u32 b = __float_as_uint(s);
    return (b & 0x80000000u) ? ~b : (b | 0x80000000u);
}
__device__ __forceinline__ float keysim(u32 k) {
    u32 b = (k & 0x80000000u) ? (k & 0x7fffffffu) : ~k;
    return __uint_as_float(b);
}

// ---------------------------------------------------------------------------
// K1: mean-pool. ids staged in LDS; fp32 dual accumulators; write x fp32,
// xh bf16 (RNE, zero-padded K 300..319), 1/max(||x||,eps).
// ---------------------------------------------------------------------------
__global__ __launch_bounds__(320) void pool_kernel(
    const int* __restrict__ ids, const float* __restrict__ W,
    float* __restrict__ x, unsigned short* __restrict__ xh,
    float* __restrict__ rxn)
{
    const int b = blockIdx.x;
    const int d = threadIdx.x;
    __shared__ int sid[SEQ];
    __shared__ float red[320];
    for (int s = d; s < SEQ; s += 320) sid[s] = ids[s * B_ + b];
    __syncthreads();
    float a0 = 0.f, a1 = 0.f;
    if (d < D_) {
        #pragma unroll 2
        for (int s = 0; s < SEQ; s += 2) {
            a0 += W[(size_t)sid[s]     * D_ + d];
            a1 += W[(size_t)sid[s + 1] * D_ + d];
        }
    }
    float xv = (a0 + a1) * (1.0f / SEQ);
    red[d] = (d < D_) ? xv * xv : 0.f;
    __syncthreads();
    if (d < 64) {
        float s = 0.f;
        #pragma unroll
        for (int i = 0; i < 5; ++i) s += red[d + i * 64];
        #pragma unroll
        for (int m = 32; m >= 1; m >>= 1) s += __shfl_xor(s, m, 64);
        if (d == 0) rxn[b] = 1.0f / fmaxf(sqrtf(s), EPS);
    }
    if (d < D_) {
        x[(size_t)b * D_ + d] = xv;
        xh[(size_t)b * DP + d] = f2bf(xv);
    } else {
        xh[(size_t)b * DP + d] = 0;
    }
}

// ---------------------------------------------------------------------------
// K2: 1/max(||t||,eps), one wave per row, float4 loads.
// ---------------------------------------------------------------------------
__global__ __launch_bounds__(256) void tnorm_kernel(
    const float* __restrict__ T, float* __restrict__ rtn)
{
    const int n = blockIdx.x * 4 + (threadIdx.x >> 6);
    const int lane = threadIdx.x & 63;
    if (n >= NT) return;
    const float4* Tr = (const float4*)(T + (size_t)n * D_);
    float4 v = Tr[lane];
    float s = v.x * v.x + v.y * v.y + v.z * v.z + v.w * v.w;
    if (lane < 11) {
        float4 w = Tr[lane + 64];
        s += w.x * w.x + w.y * w.y + w.z * w.z + w.w * w.w;
    }
    #pragma unroll
    for (int m = 32; m >= 1; m >>= 1) s += __shfl_xor(s, m, 64);
    if (lane == 0) rtn[n] = 1.0f / fmaxf(sqrtf(s), EPS);
}

// ---------------------------------------------------------------------------
// K3: hh-only bf16 GEMM (truncation-cast B on the fly) + per-(row,Nblock)
// top-1 into blockmax. 128x128 tile, BK=64, XOR-swizzled chunk LDS layout.
// ---------------------------------------------------------------------------
__global__ __launch_bounds__(256, 2) void gemm_hh_kernel(
    const unsigned short* __restrict__ Ah, const float* __restrict__ T,
    const float* __restrict__ rxn, const float* __restrict__ rtn,
    u64* __restrict__ blockmax)
{
    __shared__ unsigned short sA[BM * BK];   // 16 KB
    __shared__ unsigned short sB[BN * BK];   // 16 KB
    __shared__ u64 sBest[BM];

    const int tid = threadIdx.x;
    const int bMi = blockIdx.x, bNi = blockIdx.y;
    const int lane = tid & 63, wid = tid >> 6;
    const int wm = wid >> 1, wn = wid & 1;
    const int quad = lane >> 4, l15 = lane & 15;

    f32x4 acc[4][4] = {};

    for (int kp = 0; kp < DP; kp += BK) {
        // ---- stage A: 1024 16B-chunks, direct bf16 copy, xor-swizzled ----
        #pragma unroll
        for (int i = 0; i < 4; ++i) {
            int ch = i * 256 + tid;
            int row = ch >> 3, c = ch & 7;
            int cp = c ^ (row & 7);
            *(uint4*)&sA[row * BK + cp * 8] =
                *(const uint4*)&Ah[(size_t)(bMi * BM + row) * DP + kp + c * 8];
        }
        // ---- stage B: truncation-cast fp32 -> bf16, xor-swizzled ----
        #pragma unroll
        for (int i = 0; i < 4; ++i) {
            int ch = i * 256 + tid;
            int row = ch >> 3, c = ch & 7;
            int n = bNi * BN + row;
            int k = kp + c * 8;
            float f[8];
            if (n < NT && k + 8 <= D_) {
                float4 v0 = *(const float4*)&T[(size_t)n * D_ + k];
                float4 v1 = *(const float4*)&T[(size_t)n * D_ + k + 4];
                f[0] = v0.x; f[1] = v0.y; f[2] = v0.z; f[3] = v0.w;
                f[4] = v1.x; f[5] = v1.y; f[6] = v1.z; f[7] = v1.w;
            } else {
                #pragma unroll
                for (int j = 0; j < 8; ++j)
                    f[j] = (n < NT && k + j < D_) ? T[(size_t)n * D_ + k + j] : 0.f;
            }
            uint4 u;
            u.x = (__float_as_uint(f[0]) >> 16) | (__float_as_uint(f[1]) & 0xFFFF0000u);
            u.y = (__float_as_uint(f[2]) >> 16) | (__float_as_uint(f[3]) & 0xFFFF0000u);
            u.z = (__float_as_uint(f[4]) >> 16) | (__float_as_uint(f[5]) & 0xFFFF0000u);
            u.w = (__float_as_uint(f[6]) >> 16) | (__float_as_uint(f[7]) & 0xFFFF0000u);
            int cp = c ^ (row & 7);
            *(uint4*)&sB[row * BK + cp * 8] = u;
        }
        __syncthreads();

        #pragma unroll
        for (int s = 0; s < 2; ++s) {
            bf16x8 fa[4], fb[4];
            #pragma unroll
            for (int f = 0; f < 4; ++f) {
                int ar = wm * 64 + f * 16 + l15;
                int ac = (s * 4 + quad) ^ (ar & 7);
                fa[f] = *(const bf16x8*)&sA[ar * BK + ac * 8];
                int br = wn * 64 + f * 16 + l15;
                int bc = (s * 4 + quad) ^ (br & 7);
                fb[f] = *(const bf16x8*)&sB[br * BK + bc * 8];
            }
            #pragma unroll
            for (int fm = 0; fm < 4; ++fm)
                #pragma unroll
                for (int fn = 0; fn < 4; ++fn)
                    acc[fm][fn] = __builtin_amdgcn_mfma_f32_16x16x32_bf16(
                        fa[fm], fb[fn], acc[fm][fn], 0, 0, 0);
        }
        __syncthreads();
    }

    // ---- epilogue: per-row block-local top-1 ----
    if (tid < BM) sBest[tid] = 0ull;
    __syncthreads();
    float rt[4];
    const int gn0 = bNi * BN + wn * 64 + l15;
    #pragma unroll
    for (int fn = 0; fn < 4; ++fn)
        rt[fn] = (gn0 + fn * 16 < NT) ? rtn[gn0 + fn * 16] : 0.f;
    #pragma unroll
    for (int fm = 0; fm < 4; ++fm) {
        #pragma unroll
        for (int r = 0; r < 4; ++r) {
            int rowl = wm * 64 + fm * 16 + quad * 4 + r;   // C row = quad*4+reg
            float rx = rxn[bMi * BM + rowl];
            u64 best = 0ull;
            #pragma unroll
            for (int fn = 0; fn < 4; ++fn) {
                int gn = gn0 + fn * 16;                     // C col = lane&15
                if (gn < NT) {
                    float sim = acc[fm][fn][r] * rx * rt[fn];
                    u64 pk = ((u64)simkey(sim) << 32) | (u32)(~gn);
                    best = (pk > best) ? pk : best;
                }
            }
            #pragma unroll
            for (int m = 1; m < 16; m <<= 1) {
                u64 o = __shfl_xor(best, m, 64);
                best = (o > best) ? o : best;
            }
            if (l15 == 0) atomicMax(&sBest[rowl], best);
        }
    }
    __syncthreads();
    if (tid < BM)
        blockmax[(size_t)(bMi * BM + tid) * NBLK + bNi] = sBest[tid];
}

// ---------------------------------------------------------------------------
// K4: per row scan blockmax -> global hh max; emit qualifying blocks.
// ---------------------------------------------------------------------------
__global__ __launch_bounds__(256) void scan_kernel(
    const u64* __restrict__ blockmax, u32* __restrict__ cand,
    u32* __restrict__ count)
{
    const int row = blockIdx.x;
    const int t = threadIdx.x;
    const u64* bmr = blockmax + (size_t)row * NBLK;
    u64 m = 0ull;
    for (int j = t; j < NBLK; j += 256) { u64 e = bmr[j]; m = (e > m) ? e : m; }
    #pragma unroll
    for (int msk = 32; msk >= 1; msk >>= 1) {
        u64 o = __shfl_xor(m, msk, 64);
        m = (o > m) ? o : m;
    }
    __shared__ u64 wred[4];
    __shared__ float thr_s;
    if ((t & 63) == 0) wred[t >> 6] = m;
    __syncthreads();
    if (t == 0) {
        u64 g = wred[0];
        for (int i = 1; i < 4; ++i) g = (wred[i] > g) ? wred[i] : g;
        thr_s = keysim((u32)(g >> 32)) - MARGIN;
    }
    __syncthreads();
    float thr = thr_s;
    for (int j = t; j < NBLK; j += 256) {
        float s = keysim((u32)(bmr[j] >> 32));
        if (s >= thr) {               // NaN (empty entry) compares false
            u32 p = atomicAdd(count, 1u);
            if (p < CAND_MAX) cand[p] = ((u32)row << 10) | (u32)j;
        }
    }
}

// ---------------------------------------------------------------------------
// K5: exact fp32 rescore of all 128 columns of each qualifying block.
// ---------------------------------------------------------------------------
__global__ __launch_bounds__(256) void rescore_kernel(
    const u32* __restrict__ cand, const u32* __restrict__ count,
    const float* __restrict__ x, const float* __restrict__ T,
    const float* __restrict__ rxn, u64* __restrict__ winner)
{
    u32 cnt = *count; if (cnt > CAND_MAX) cnt = CAND_MAX;
    if (blockIdx.x >= cnt) return;
    u32 c = cand[blockIdx.x];
    const int row = c >> 10, bN = c & 1023;
    __shared__ float4 xs4[75];
    const int t = threadIdx.x;
    if (t < 75) xs4[t] = *(const float4*)&x[(size_t)row * D_ + t * 4];
    __syncthreads();
    const float rx = rxn[row];
    const int w = t >> 6, lane = t & 63;
    u64 best = 0ull;
    for (int cc = 0; cc < 32; ++cc) {
        int n = bN * BN + w * 32 + cc;
        if (n >= NT) break;                      // wave-uniform
        const float4* Tr = (const float4*)(T + (size_t)n * D_);
        float4 v = Tr[lane], xv = xs4[lane];
        float dot = v.x * xv.x + v.y * xv.y + v.z * xv.z + v.w * xv.w;
        float tt  = v.x * v.x + v.y * v.y + v.z * v.z + v.w * v.w;
        if (lane < 11) {
            float4 v2 = Tr[lane + 64], x2 = xs4[lane + 64];
            dot += v2.x * x2.x + v2.y * x2.y + v2.z * x2.z + v2.w * x2.w;
            tt  += v2.x * v2.x + v2.y * v2.y + v2.z * v2.z + v2.w * v2.w;
        }
        #pragma unroll
        for (int m = 32; m >= 1; m >>= 1) {
            dot += __shfl_xor(dot, m, 64);
            tt  += __shfl_xor(tt, m, 64);
        }
        float sim = dot * rx / fmaxf(sqrtf(tt), EPS);
        u64 pk = ((u64)simkey(sim) << 32) | (u32)(~n);
        best = (pk > best) ? pk : best;
    }
    if (lane == 0 && best) atomicMax(&winner[row], best);
}

// ---------------------------------------------------------------------------
// K6: decode winner, fp64 rescore for score, label gather.
// ---------------------------------------------------------------------------
__global__ __launch_bounds__(64) void final_kernel(
    const u64* __restrict__ winner, const float* __restrict__ x,
    const float* __restrict__ T, const int* __restrict__ y_train,
    float* __restrict__ out)
{
    const int b = blockIdx.x;
    const int lane = threadIdx.x;
    int idx = (int)(~(u32)winner[b]);
    if (idx < 0 || idx >= NT) idx = 0;
    double dot = 0.0, nx = 0.0, nt = 0.0;
    for (int d = lane; d < D_; d += 64) {
        double xv = (double)x[(size_t)b * D_ + d];
        double tv = (double)T[(size_t)idx * D_ + d];
        dot += xv * tv; nx += xv * xv; nt += tv * tv;
    }
    #pragma unroll
    for (int m = 32; m >= 1; m >>= 1) {
        dot += __shfl_xor(dot, m, 64);
        nx  += __shfl_xor(nx, m, 64);
        nt  += __shfl_xor(nt, m, 64);
    }
    if (lane == 0) {
        double score = dot / (fmax(sqrt(nx), (double)EPS) * fmax(sqrt(nt), (double)EPS));
        out[b]      = (float)y_train[idx];
        out[B_ + b] = (float)score;
    }
}

// ---------------------------------------------------------------------------
extern "C" void kernel_launch(void* const* d_in, const int* in_sizes, int n_in,
                              void* d_out, int out_size, void* d_ws, size_t ws_size,
                              hipStream_t stream)
{
    const int*   ids = (const int*)d_in[0];
    const float* W   = (const float*)d_in[1];
    const float* T   = (const float*)d_in[2];
    const int*   y   = (const int*)d_in[3];

    char* ws = (char*)d_ws;
    size_t off = 0;
    float* x           = (float*)(ws + off);          off += (size_t)B_ * D_ * 4;      // 1,228,800
    unsigned short* xh = (unsigned short*)(ws + off); off += (size_t)B_ * DP * 2;      //   655,360
    float* rxn         = (float*)(ws + off);          off += (size_t)B_ * 4;           //     4,096
    float* rtn         = (float*)(ws + off);          off += 400128;                   //   400,128
    u64* blockmax      = (u64*)(ws + off);            off += (size_t)B_ * NBLK * 8;    // 6,406,144
    u32* cand          = (u32*)(ws + off);            off += (size_t)CAND_MAX * 4;     //    16,384
    u64* winner        = (u64*)(ws + off);            off += (size_t)B_ * 8;           //     8,192
    u32* count         = (u32*)(ws + off);            off += 256;                      //   total ~8.7 MB

    // zero winner + count (adjacent)
    hipMemsetAsync(winner, 0, (size_t)B_ * 8 + 256, stream);
    pool_kernel<<<B_, 320, 0, stream>>>(ids, W, x, xh, rxn);
    tnorm_kernel<<<(NT + 3) / 4, 256, 0, stream>>>(T, rtn);
    gemm_hh_kernel<<<dim3(B_ / BM, NBLK), 256, 0, stream>>>(xh, T, rxn, rtn, blockmax);
    scan_kernel<<<B_, 256, 0, stream>>>(blockmax, cand, count);
    rescore_kernel<<<CAND_MAX, 256, 0, stream>>>(cand, count, x, T, rxn, winner);
    final_kernel<<<B_, 64, 0, stream>>>(winner, x, T, y, (float*)d_out);
}

// Round 3
// 397.628 us; speedup vs baseline: 1.6187x; 1.3271x over previous
//
#include <hip/hip_runtime.h>
#include <hip/hip_bf16.h>
#include <stdint.h>

#define EPS 1e-8f

typedef __attribute__((ext_vector_type(8))) short bf16x8;
typedef __attribute__((ext_vector_type(4))) float f32x4;
typedef unsigned long long u64;
typedef unsigned int u32;

constexpr int SEQ = 200;
constexpr int B_  = 1024;    // batch
constexpr int D_  = 300;     // embedding dim
constexpr int DP  = 320;     // K padded
constexpr int NT  = 100000;  // train rows
constexpr int BM = 128, BN = 128, BK = 64;
constexpr int NSTRIP = 784;            // padded strip count (multiple of 8)
constexpr int NTP = NSTRIP * BN;       // 100352 padded rows
constexpr int CAND_MAX = 4096;
#define MARGIN 2e-3f

__device__ __forceinline__ unsigned short f2bf(float f) {   // RNE
    u32 b = __float_as_uint(f);
    return (unsigned short)((b + 0x7fffu + ((b >> 16) & 1u)) >> 16);
}
__device__ __forceinline__ u32 simkey(float s) {            // order-preserving
    u32 b = __float_as_uint(s);
    return (b & 0x80000000u) ? ~b : (b | 0x80000000u);
}
__device__ __forceinline__ float keysim(u32 k) {
    u32 b = (k & 0x80000000u) ? (k & 0x7fffffffu) : ~k;
    return __uint_as_float(b);
}
__device__ __forceinline__ void gload_lds16(const void* g, void* l) {
    __builtin_amdgcn_global_load_lds(
        (const __attribute__((address_space(1))) unsigned int*)g,
        (__attribute__((address_space(3))) unsigned int*)l, 16, 0, 0);
}

// ---------------------------------------------------------------------------
// K1: mean-pool, seq split over 2 halves (640 threads). Writes x fp32,
// xh bf16 (RNE, zero-padded cols 300..319), 1/max(||x||,eps).
// ---------------------------------------------------------------------------
__global__ __launch_bounds__(640) void pool_kernel(
    const int* __restrict__ ids, const float* __restrict__ W,
    float* __restrict__ x, unsigned short* __restrict__ xh,
    float* __restrict__ rxn)
{
    const int b = blockIdx.x;
    const int tid = threadIdx.x;
    __shared__ int sid[SEQ];
    __shared__ float part[640];
    for (int s = tid; s < SEQ; s += 640) sid[s] = ids[s * B_ + b];
    __syncthreads();
    const int half = (tid >= 320) ? 1 : 0;
    const int d = tid - half * 320;
    float a0 = 0.f, a1 = 0.f;
    if (d < D_) {
        const int s0 = half * (SEQ / 2);
        #pragma unroll 2
        for (int s = 0; s < SEQ / 2; s += 2) {
            a0 += W[(size_t)sid[s0 + s]     * D_ + d];
            a1 += W[(size_t)sid[s0 + s + 1] * D_ + d];
        }
    }
    part[tid] = a0 + a1;
    __syncthreads();
    float xv = 0.f;
    if (tid < 320) xv = (part[tid] + part[tid + 320]) * (1.0f / SEQ);
    __syncthreads();
    if (tid < 320) part[tid] = (tid < D_) ? xv * xv : 0.f;
    __syncthreads();
    if (tid < 64) {
        float s = 0.f;
        #pragma unroll
        for (int i = 0; i < 5; ++i) s += part[tid + i * 64];
        #pragma unroll
        for (int m = 32; m >= 1; m >>= 1) s += __shfl_xor(s, m, 64);
        if (tid == 0) rxn[b] = 1.0f / fmaxf(sqrtf(s), EPS);
    }
    if (tid < 320) {
        if (tid < D_) {
            x[(size_t)b * D_ + tid] = xv;
            xh[(size_t)b * DP + tid] = f2bf(xv);
        } else {
            xh[(size_t)b * DP + tid] = 0;
        }
    }
}

// ---------------------------------------------------------------------------
// K2: 1/max(||t||,eps) + convert T -> Tb bf16 (RNE), rows padded to NTP,
// cols padded to DP with zeros. One wave per row.
// ---------------------------------------------------------------------------
__global__ __launch_bounds__(256) void tnorm_kernel(
    const float* __restrict__ T, float* __restrict__ rtn,
    unsigned short* __restrict__ Tb)
{
    const int n = blockIdx.x * 4 + (threadIdx.x >> 6);
    const int lane = threadIdx.x & 63;
    if (n >= NTP) return;
    ushort4* tb = (ushort4*)(Tb + (size_t)n * DP);   // 80 ushort4 per row
    if (n >= NT) {                                    // zero pad rows
        ushort4 z = {0, 0, 0, 0};
        tb[lane] = z;
        if (lane < 16) tb[64 + lane] = z;
        return;
    }
    const float4* Tr = (const float4*)(T + (size_t)n * D_);
    float4 v = Tr[lane];
    float s = v.x * v.x + v.y * v.y + v.z * v.z + v.w * v.w;
    ushort4 o; o.x = f2bf(v.x); o.y = f2bf(v.y); o.z = f2bf(v.z); o.w = f2bf(v.w);
    tb[lane] = o;
    if (lane < 16) {
        if (lane < 11) {
            float4 w = Tr[64 + lane];
            s += w.x * w.x + w.y * w.y + w.z * w.z + w.w * w.w;
            ushort4 p; p.x = f2bf(w.x); p.y = f2bf(w.y); p.z = f2bf(w.z); p.w = f2bf(w.w);
            tb[64 + lane] = p;
        } else {
            ushort4 z = {0, 0, 0, 0};
            tb[64 + lane] = z;
        }
    }
    #pragma unroll
    for (int m = 32; m >= 1; m >>= 1) s += __shfl_xor(s, m, 64);
    if (lane == 0) rtn[n] = 1.0f / fmaxf(sqrtf(s), EPS);
}

// ---------------------------------------------------------------------------
// K3: hh bf16 GEMM via global_load_lds (width 16, per-lane xor-swizzled
// global addresses -> swizzled LDS without per-lane LDS scatter).
// XCD-aware block swizzle: all 8 M-tiles of a strip share g%8 (same XCD).
// Epilogue: per-(row,strip) max sim key (u32) -> blockmax.
// ---------------------------------------------------------------------------
__global__ __launch_bounds__(256, 3) void gemm_hh_kernel(
    const unsigned short* __restrict__ Ah, const unsigned short* __restrict__ Tb,
    const float* __restrict__ rxn, const float* __restrict__ rtn,
    u32* __restrict__ blockmax)
{
    __shared__ unsigned short sA[BM * BK];   // 16 KB
    __shared__ unsigned short sB[BN * BK];   // 16 KB
    __shared__ u32 sBest[BM];

    const int tid = threadIdx.x;
    const int g = blockIdx.x;
    const int k8 = g & 7;
    const int t = g >> 3;
    const int bMi = t & 7;                       // M-tile
    const int strip = ((t >> 3) << 3) | k8;      // N-strip, same XCD for all bMi

    const int lane = tid & 63, wid = tid >> 6;
    const int wm = wid >> 1, wn = wid & 1;
    const int quad = lane >> 4, l15 = lane & 15;

    // staging geometry: call j in [0,4): chunk L = (j*4+wid)*64 + lane.
    // LDS gets chunk L at byte L*16 (HW: base+lane*16). We choose the GLOBAL
    // chunk (r = L>>3, c = (L&7) ^ (r&7)) so LDS ends up xor-swizzled.
    const unsigned short* pA[4];
    const unsigned short* pB[4];
    int ldsoff[4];
    #pragma unroll
    for (int j = 0; j < 4; ++j) {
        int L = (j * 4 + wid) * 64 + lane;
        int r = L >> 3;
        int c = (L & 7) ^ (r & 7);
        ldsoff[j] = (j * 4 + wid) * 1024;
        pA[j] = Ah + (size_t)(bMi * BM + r) * DP + c * 8;
        pB[j] = Tb + (size_t)(strip * BN + r) * DP + c * 8;
    }

    f32x4 acc[4][4] = {};

    for (int kp = 0; kp < DP; kp += BK) {
        #pragma unroll
        for (int j = 0; j < 4; ++j)
            gload_lds16(pA[j] + kp, (char*)sA + ldsoff[j]);
        #pragma unroll
        for (int j = 0; j < 4; ++j)
            gload_lds16(pB[j] + kp, (char*)sB + ldsoff[j]);
        __syncthreads();

        #pragma unroll
        for (int s = 0; s < 2; ++s) {
            bf16x8 fa[4], fb[4];
            #pragma unroll
            for (int f = 0; f < 4; ++f) {
                int ar = wm * 64 + f * 16 + l15;
                int ac = (s * 4 + quad) ^ (ar & 7);
                fa[f] = *(const bf16x8*)&sA[ar * BK + ac * 8];
                int br = wn * 64 + f * 16 + l15;
                int bc = (s * 4 + quad) ^ (br & 7);
                fb[f] = *(const bf16x8*)&sB[br * BK + bc * 8];
            }
            #pragma unroll
            for (int fm = 0; fm < 4; ++fm)
                #pragma unroll
                for (int fn = 0; fn < 4; ++fn)
                    acc[fm][fn] = __builtin_amdgcn_mfma_f32_16x16x32_bf16(
                        fa[fm], fb[fn], acc[fm][fn], 0, 0, 0);
        }
        __syncthreads();
    }

    // ---- epilogue: per-row max sim key ----
    if (tid < BM) sBest[tid] = 0u;
    __syncthreads();
    float rt[4];
    const int gn0 = strip * BN + wn * 64 + l15;
    #pragma unroll
    for (int fn = 0; fn < 4; ++fn)
        rt[fn] = (gn0 + fn * 16 < NT) ? rtn[gn0 + fn * 16] : 0.f;
    #pragma unroll
    for (int fm = 0; fm < 4; ++fm) {
        #pragma unroll
        for (int r = 0; r < 4; ++r) {
            int rowl = wm * 64 + fm * 16 + quad * 4 + r;   // C row = quad*4+reg
            float rx = rxn[bMi * BM + rowl];
            u32 bk = 0u;
            #pragma unroll
            for (int fn = 0; fn < 4; ++fn) {
                float sim = acc[fm][fn][r] * rx * rt[fn];
                u32 k = simkey(sim);
                bk = (k > bk) ? k : bk;
            }
            #pragma unroll
            for (int m = 1; m < 16; m <<= 1) {
                u32 o = __shfl_xor(bk, m, 64);
                bk = (o > bk) ? o : bk;
            }
            if (l15 == 0) atomicMax(&sBest[rowl], bk);
        }
    }
    __syncthreads();
    if (tid < BM)
        blockmax[(size_t)(bMi * BM + tid) * NSTRIP + strip] = sBest[tid];
}

// ---------------------------------------------------------------------------
// K4: per-row scan of blockmax -> threshold; emit qualifying strips.
// ---------------------------------------------------------------------------
__global__ __launch_bounds__(256) void scan_kernel(
    const u32* __restrict__ blockmax, u32* __restrict__ cand,
    u32* __restrict__ count)
{
    const int row = blockIdx.x;
    const int t = threadIdx.x;
    const u32* bmr = blockmax + (size_t)row * NSTRIP;
    u32 m = 0u;
    for (int j = t; j < NSTRIP; j += 256) { u32 e = bmr[j]; m = (e > m) ? e : m; }
    #pragma unroll
    for (int msk = 32; msk >= 1; msk >>= 1) {
        u32 o = __shfl_xor(m, msk, 64);
        m = (o > m) ? o : m;
    }
    __shared__ u32 wred[4];
    __shared__ float thr_s;
    if ((t & 63) == 0) wred[t >> 6] = m;
    __syncthreads();
    if (t == 0) {
        u32 gmx = wred[0];
        for (int i = 1; i < 4; ++i) gmx = (wred[i] > gmx) ? wred[i] : gmx;
        thr_s = keysim(gmx) - MARGIN;
    }
    __syncthreads();
    float thr = thr_s;
    for (int j = t; j < NSTRIP; j += 256) {
        if (keysim(bmr[j]) >= thr) {
            u32 p = atomicAdd(count, 1u);
            if (p < CAND_MAX) cand[p] = ((u32)row << 10) | (u32)j;
        }
    }
}

// ---------------------------------------------------------------------------
// K5: exact fp32 rescore of all 128 columns of each qualifying strip.
// ---------------------------------------------------------------------------
__global__ __launch_bounds__(256) void rescore_kernel(
    const u32* __restrict__ cand, const u32* __restrict__ count,
    const float* __restrict__ x, const float* __restrict__ T,
    const float* __restrict__ rxn, u64* __restrict__ winner)
{
    u32 cnt = *count; if (cnt > CAND_MAX) cnt = CAND_MAX;
    if (blockIdx.x >= cnt) return;
    u32 c = cand[blockIdx.x];
    const int row = c >> 10, strip = c & 1023;
    __shared__ float4 xs4[75];
    const int t = threadIdx.x;
    if (t < 75) xs4[t] = *(const float4*)&x[(size_t)row * D_ + t * 4];
    __syncthreads();
    const float rx = rxn[row];
    const int w = t >> 6, lane = t & 63;
    u64 best = 0ull;
    for (int cc = 0; cc < 32; ++cc) {
        int n = strip * BN + w * 32 + cc;
        if (n >= NT) break;                      // wave-uniform
        const float4* Tr = (const float4*)(T + (size_t)n * D_);
        float4 v = Tr[lane], xv = xs4[lane];
        float dot = v.x * xv.x + v.y * xv.y + v.z * xv.z + v.w * xv.w;
        float tt  = v.x * v.x + v.y * v.y + v.z * v.z + v.w * v.w;
        if (lane < 11) {
            float4 v2 = Tr[lane + 64], x2 = xs4[lane + 64];
            dot += v2.x * x2.x + v2.y * x2.y + v2.z * x2.z + v2.w * x2.w;
            tt  += v2.x * v2.x + v2.y * v2.y + v2.z * v2.z + v2.w * v2.w;
        }
        #pragma unroll
        for (int m = 32; m >= 1; m >>= 1) {
            dot += __shfl_xor(dot, m, 64);
            tt  += __shfl_xor(tt, m, 64);
        }
        float sim = dot * rx / fmaxf(sqrtf(tt), EPS);
        u64 pk = ((u64)simkey(sim) << 32) | (u32)(~n);
        best = (pk > best) ? pk : best;
    }
    if (lane == 0 && best) atomicMax(&winner[row], best);
}

// ---------------------------------------------------------------------------
// K6: decode winner, fp64 rescore for score, label gather.
// ---------------------------------------------------------------------------
__global__ __launch_bounds__(64) void final_kernel(
    const u64* __restrict__ winner, const float* __restrict__ x,
    const float* __restrict__ T, const int* __restrict__ y_train,
    float* __restrict__ out)
{
    const int b = blockIdx.x;
    const int lane = threadIdx.x;
    int idx = (int)(~(u32)winner[b]);
    if (idx < 0 || idx >= NT) idx = 0;
    double dot = 0.0, nx = 0.0, nt = 0.0;
    for (int d = lane; d < D_; d += 64) {
        double xv = (double)x[(size_t)b * D_ + d];
        double tv = (double)T[(size_t)idx * D_ + d];
        dot += xv * tv; nx += xv * xv; nt += tv * tv;
    }
    #pragma unroll
    for (int m = 32; m >= 1; m >>= 1) {
        dot += __shfl_xor(dot, m, 64);
        nx  += __shfl_xor(nx, m, 64);
        nt  += __shfl_xor(nt, m, 64);
    }
    if (lane == 0) {
        double score = dot / (fmax(sqrt(nx), (double)EPS) * fmax(sqrt(nt), (double)EPS));
        out[b]      = (float)y_train[idx];
        out[B_ + b] = (float)score;
    }
}

// ---------------------------------------------------------------------------
extern "C" void kernel_launch(void* const* d_in, const int* in_sizes, int n_in,
                              void* d_out, int out_size, void* d_ws, size_t ws_size,
                              hipStream_t stream)
{
    const int*   ids = (const int*)d_in[0];
    const float* W   = (const float*)d_in[1];
    const float* T   = (const float*)d_in[2];
    const int*   y   = (const int*)d_in[3];

    char* ws = (char*)d_ws;
    size_t off = 0;
    float* x           = (float*)(ws + off);          off += (size_t)B_ * D_ * 4;        // 1,228,800
    unsigned short* xh = (unsigned short*)(ws + off); off += (size_t)B_ * DP * 2;        //   655,360
    float* rxn         = (float*)(ws + off);          off += (size_t)B_ * 4;             //     4,096
    float* rtn         = (float*)(ws + off);          off += (size_t)NT * 4;             //   400,000
    unsigned short* Tb = (unsigned short*)(ws + off); off += (size_t)NTP * DP * 2;       // 64,225,280
    u32* blockmax      = (u32*)(ws + off);            off += (size_t)B_ * NSTRIP * 4;    //  3,211,264
    u32* cand          = (u32*)(ws + off);            off += (size_t)CAND_MAX * 4;       //     16,384
    u64* winner        = (u64*)(ws + off);            off += (size_t)B_ * 8;             //      8,192
    u32* count         = (u32*)(ws + off);            off += 256;                        // total ~67 MB

    hipMemsetAsync(winner, 0, (size_t)B_ * 8 + 256, stream);   // winner + count
    pool_kernel<<<B_, 640, 0, stream>>>(ids, W, x, xh, rxn);
    tnorm_kernel<<<NTP / 4, 256, 0, stream>>>(T, rtn, Tb);
    gemm_hh_kernel<<<8 * NSTRIP, 256, 0, stream>>>(xh, Tb, rxn, rtn, blockmax);
    scan_kernel<<<B_, 256, 0, stream>>>(blockmax, cand, count);
    rescore_kernel<<<CAND_MAX, 256, 0, stream>>>(cand, count, x, T, rxn, winner);
    final_kernel<<<B_, 64, 0, stream>>>(winner, x, T, y, (float*)d_out);
}